// Round 4
// baseline (1091.200 us; speedup 1.0000x reference)
//
#include <hip/hip_runtime.h>
#include <math.h>

#define NX 256
#define NY 256
#define N_STEPS 300
#define N_CELLS (NX * NY)
#define TILE 16
#define HALO 8
#define LSTR 36              // LDS row stride in floats
#define LROWS 34             // rows -1..32
#define LIDX(rr, cc) (((rr) + 1) * LSTR + ((cc) + 2))
#define NBLKS 256

// f32 constants (double-precision fold -> f32)
#define kINV_DX       1280.0f
#define kINV_DY       1280.0f
#define kDT           2.5e-5f
#define kMU           25000.0f
#define kETA          0.1f
#define kDT_OVER_RHO  2.5e-8f
#define kONE_MINUS_BD 0.99999975f
#define kNEG_INV_2SIG2 (-55555.5546875f)
#define kDX           7.8125e-4f
#define kEPS          1e-8f

__device__ __forceinline__ float dprof(int k) {
    int m = min(k, NX - 1 - k);
    if (m >= 20) return 1.0f;
    float arg = 3.14159265358979f * (float)(20 - m) / 20.0f;
    return 1.0f - 0.05f * (0.5f + 0.5f * cosf(arg));
}

// grid-wide barrier: monotonic arrival counter + published phase flag.
// Producer side: __syncthreads drains each wave's vmem; thread0 release-fence
// then atomic arrive. Last arriver publishes phase. Readers acquire-fence.
__device__ __forceinline__ void grid_sync(unsigned* counter, unsigned* flag,
                                          unsigned phase) {
    __syncthreads();
    if (threadIdx.x == 0) {
        __threadfence();
        unsigned old = __hip_atomic_fetch_add(counter, 1u, __ATOMIC_RELAXED,
                                              __HIP_MEMORY_SCOPE_AGENT);
        if (old == phase * NBLKS - 1u) {
            __hip_atomic_store(flag, phase, __ATOMIC_RELEASE,
                               __HIP_MEMORY_SCOPE_AGENT);
        } else {
            while (__hip_atomic_load(flag, __ATOMIC_ACQUIRE,
                                     __HIP_MEMORY_SCOPE_AGENT) < phase) {
                __builtin_amdgcn_s_sleep(4);
            }
        }
        __threadfence();
    }
    __syncthreads();
}

struct Ctx {
    int r, c0, g;
    int gi, gj0;
    bool inD, fwdX, fwdY1, backX, backY0, owned, haloUp, haloLeft;
    float damp0, damp1, xi, yj0, yj1;
};

template <int K, bool FIRST, bool LAST>
__device__ __forceinline__ void run_chunk(
    const Ctx& C, int t0,
    const float* __restrict__ vz_in,
    const float* __restrict__ sxz_in,
    const float* __restrict__ syz_in,
    float* __restrict__ vz_out,
    float* __restrict__ sxz_out,
    float* __restrict__ syz_out,
    const float2* __restrict__ traj,
    float* __restrict__ out,
    float (*s_vz)[LROWS * LSTR])
{
    // trajectory for this chunk
    float trx[K], tryy[K];
    #pragma unroll
    for (int s = 0; s < K; ++s) {
        float2 t2 = traj[t0 + s];
        trx[s] = t2.x; tryy[s] = t2.y;
    }

    // load state
    float vz0 = 0.f, vz1 = 0.f, sx0 = 0.f, sx1 = 0.f, sy0 = 0.f, sy1 = 0.f;
    float sxm0 = 0.f, sxm1 = 0.f, symv = 0.f;
    if (!FIRST) {
        if (C.inD) {
            float2 v2 = *(const float2*)&vz_in[C.g];  vz0 = v2.x; vz1 = v2.y;
            float2 a2 = *(const float2*)&sxz_in[C.g]; sx0 = a2.x; sx1 = a2.y;
            float2 b2 = *(const float2*)&syz_in[C.g]; sy0 = b2.x; sy1 = b2.y;
        }
        if (C.haloUp)   { float2 m2 = *(const float2*)&sxz_in[C.g - NY]; sxm0 = m2.x; sxm1 = m2.y; }
        if (C.haloLeft) { symv = syz_in[C.g - 1]; }
    }
    // caller guarantees a block barrier precedes (grid_sync or initial sync)
    *(float2*)&s_vz[0][LIDX(C.r, C.c0)] = make_float2(vz0, vz1);
    __syncthreads();

    #pragma unroll
    for (int s = 0; s < K; ++s) {
        const int cur = s & 1, nxt = cur ^ 1;
        const float x_t = trx[s], y_t = tryy[s];

        const float2 vp = *(const float2*)&s_vz[cur][LIDX(C.r + 1, C.c0)];
        const float2 vm = *(const float2*)&s_vz[cur][LIDX(C.r - 1, C.c0)];
        const float vr2 = s_vz[cur][LIDX(C.r, C.c0 + 2)];
        const float vl1 = s_vz[cur][LIDX(C.r, C.c0 - 1)];

        const float dvx0 = C.fwdX  ? (vp.x - vz0) * kINV_DX : 0.0f;
        const float dvx1 = C.fwdX  ? (vp.y - vz1) * kINV_DX : 0.0f;
        const float dvy0 = (vz1 - vz0) * kINV_DY;
        const float dvy1 = C.fwdY1 ? (vr2 - vz1) * kINV_DY : 0.0f;

        sx0 += dvx0 * kDT; sx1 += dvx1 * kDT;
        sy0 += dvy0 * kDT; sy1 += dvy1 * kDT;
        const float gx0 = kMU * sx0 + kETA * dvx0;
        const float gx1 = kMU * sx1 + kETA * dvx1;
        const float gy0 = kMU * sy0 + kETA * dvy0;
        const float gy1 = kMU * sy1 + kETA * dvy1;

        const float dxm0 = (vz0 - vm.x) * kINV_DX;
        const float dxm1 = (vz1 - vm.y) * kINV_DX;
        sxm0 += dxm0 * kDT; sxm1 += dxm1 * kDT;
        const float gxm0 = kMU * sxm0 + kETA * dxm0;
        const float gxm1 = kMU * sxm1 + kETA * dxm1;
        const float dym = (vz0 - vl1) * kINV_DY;
        symv += dym * kDT;
        const float gym = kMU * symv + kETA * dym;

        const float dsx0 = C.backX  ? (gx0 - gxm0) * kINV_DX : 0.0f;
        const float dsx1 = C.backX  ? (gx1 - gxm1) * kINV_DX : 0.0f;
        const float dsy0 = C.backY0 ? (gy0 - gym) * kINV_DY : 0.0f;
        const float dsy1 = (gy1 - gy0) * kINV_DY;

        const float rx  = C.xi  - x_t;
        const float ry0 = C.yj0 - y_t;
        const float ry1 = C.yj1 - y_t;
        const float src0 = expf((rx * rx + ry0 * ry0) * kNEG_INV_2SIG2);
        const float src1 = expf((rx * rx + ry1 * ry1) * kNEG_INV_2SIG2);

        vz0 = (vz0 + kDT_OVER_RHO * (dsx0 + dsy0 + src0)) * kONE_MINUS_BD * C.damp0;
        vz1 = (vz1 + kDT_OVER_RHO * (dsx1 + dsy1 + src1)) * kONE_MINUS_BD * C.damp1;

        *(float2*)&s_vz[nxt][LIDX(C.r, C.c0)] = make_float2(vz0, vz1);

        if (C.owned) {
            *(float2*)&out[(size_t)(t0 + s) * N_CELLS + C.g] = make_float2(vz0, vz1);
            const float sm0 = sqrtf(gx0 * gx0 + gy0 * gy0 + kEPS);
            const float sm1 = sqrtf(gx1 * gx1 + gy1 * gy1 + kEPS);
            *(float2*)&out[(size_t)(N_STEPS + t0 + s) * N_CELLS + C.g] = make_float2(sm0, sm1);
        }
        __syncthreads();
    }

    if (!LAST && C.owned) {
        *(float2*)&vz_out[C.g]  = make_float2(vz0, vz1);
        *(float2*)&sxz_out[C.g] = make_float2(sx0, sx1);
        *(float2*)&syz_out[C.g] = make_float2(sy0, sy1);
    }
}

__global__ __launch_bounds__(512, 2) void persistent_kernel(
    const float2* __restrict__ traj,
    float* __restrict__ out,
    float* __restrict__ ws,
    unsigned* __restrict__ bar)
{
    __shared__ float s_vz[2][LROWS * LSTR];

    float* vzS[2]  = { ws + 0 * N_CELLS, ws + 1 * N_CELLS };
    float* sxzS[2] = { ws + 2 * N_CELLS, ws + 3 * N_CELLS };
    float* syzS[2] = { ws + 4 * N_CELLS, ws + 5 * N_CELLS };

    const int tid = threadIdx.x;
    Ctx C;
    C.r   = tid >> 4;
    C.c0  = (tid & 15) << 1;
    C.gi  = (int)blockIdx.y * TILE + C.r  - HALO;
    C.gj0 = (int)blockIdx.x * TILE + C.c0 - HALO;
    C.g   = C.gi * NY + C.gj0;

    const bool rowOK = (C.gi >= 0) && (C.gi < NX);
    const bool colOK = (C.gj0 >= 0) && (C.gj0 < NY);
    C.inD    = rowOK && colOK;
    C.fwdX   = (C.gi < NX - 1);
    C.fwdY1  = (C.gj0 + 1 < NY - 1);
    C.backX  = (C.gi > 0);
    C.backY0 = (C.gj0 > 0);
    C.haloUp   = (C.gi - 1 >= 0) && (C.gi - 1 < NX) && colOK;
    C.haloLeft = rowOK && (C.gj0 - 1 >= 0);

    const float dpx = rowOK ? dprof(C.gi) : 0.0f;
    C.damp0 = C.inD ? dpx * dprof(C.gj0)     : 0.0f;
    C.damp1 = C.inD ? dpx * dprof(C.gj0 + 1) : 0.0f;
    C.xi  = ((float)C.gi + 0.5f) * kDX;
    C.yj0 = ((float)C.gj0 + 0.5f) * kDX;
    C.yj1 = ((float)C.gj0 + 1.5f) * kDX;

    C.owned = (C.r >= HALO) && (C.r < HALO + TILE) &&
              (C.c0 >= HALO) && (C.c0 + 1 < HALO + TILE);

    // zero LDS once (pads stay zero forever; out-of-domain cells rewrite 0 each step)
    for (int idx = tid; idx < 2 * LROWS * LSTR; idx += 512)
        ((float*)s_vz)[idx] = 0.0f;
    __syncthreads();

    // chunk 0: no state input, writes set 0
    run_chunk<8, true, false>(C, 0,
        vzS[0], sxzS[0], syzS[0], vzS[0], sxzS[0], syzS[0], traj, out, s_vz);

    // chunks 1..36: read set (c-1)&1, write set c&1
    for (int c = 1; c < 37; ++c) {
        grid_sync(bar, bar + 1, (unsigned)c);
        const int rs = (c - 1) & 1, wsI = c & 1;
        run_chunk<8, false, false>(C, c * 8,
            vzS[rs], sxzS[rs], syzS[rs], vzS[wsI], sxzS[wsI], syzS[wsI],
            traj, out, s_vz);
    }

    // tail chunk: 4 steps, reads set 0 (chunk 36 wrote set 0), no state store
    grid_sync(bar, bar + 1, 37u);
    run_chunk<4, false, true>(C, 296,
        vzS[0], sxzS[0], syzS[0], vzS[1], sxzS[1], syzS[1], traj, out, s_vz);
}

extern "C" void kernel_launch(void* const* d_in, const int* in_sizes, int n_in,
                              void* d_out, int out_size, void* d_ws, size_t ws_size,
                              hipStream_t stream) {
    const float2* traj = (const float2*)d_in[0];
    float* out = (float*)d_out;
    float* ws  = (float*)d_ws;
    unsigned* bar = (unsigned*)((char*)d_ws + (size_t)6 * N_CELLS * sizeof(float));

    // barrier counter+flag must start at 0 every launch (deterministic replays)
    hipMemsetAsync(bar, 0, 2 * sizeof(unsigned), stream);

    void* args[] = { (void*)&traj, (void*)&out, (void*)&ws, (void*)&bar };
    hipLaunchCooperativeKernel((const void*)persistent_kernel,
                               dim3(NX / TILE, NY / TILE), dim3(512),
                               args, 0, stream);
}

// Round 5
// 317.958 us; speedup vs baseline: 3.4319x; 3.4319x over previous
//
#include <hip/hip_runtime.h>
#include <math.h>

#define NX 256
#define NY 256
#define N_STEPS 300
#define N_CELLS (NX * NY)
#define TILE 16
#define HALO 16
#define RDIM 48               // region = TILE + 2*HALO
#define LSTR 56               // LDS row stride (floats): 48 cols + 4 pad left + 4 right, float4-aligned
#define LROWS 50              // rows -1..48
#define LIDX(rr, cc) (((rr) + 1) * LSTR + ((cc) + 4))
#define NTHREADS 576          // 48 rows x 12 groups of 4 cols

// f32 constants (double-precision fold -> f32)
#define kINV_DX       1280.0f
#define kINV_DY       1280.0f
#define kDT           2.5e-5f
#define kMU           25000.0f
#define kETA          0.1f
#define kDT_OVER_RHO  2.5e-8f
#define kONE_MINUS_BD 0.99999975f
#define kNEG_INV_2SIG2 (-55555.5546875f)   // -1/(2*0.003^2)
#define kDX           7.8125e-4f
#define kEPS          1e-8f

// PML damping profile value for 1-D global index k (0..255)
__device__ __forceinline__ float dprof(int k) {
    int m = min(k, NX - 1 - k);
    if (m >= 20) return 1.0f;
    float arg = 3.14159265358979f * (float)(20 - m) / 20.0f;
    return 1.0f - 0.05f * (0.5f + 0.5f * cosf(arg));
}

template <int K, bool FIRST, bool LAST>
__global__ __launch_bounds__(NTHREADS) void fused_kernel(
    const float* __restrict__ vz_in,
    const float* __restrict__ sxz_in,
    const float* __restrict__ syz_in,
    float* __restrict__ vz_out,
    float* __restrict__ sxz_out,
    float* __restrict__ syz_out,
    const float2* __restrict__ traj,
    int t0,
    float* __restrict__ out)
{
    __shared__ float s_vz[2][LROWS * LSTR];

    const int tid = threadIdx.x;
    const int r   = tid / 12;            // region row, 0..47
    const int m   = tid - r * 12;        // col group, 0..11
    const int c0  = m << 2;              // region col base, 0,4,...,44

    const int gi  = (int)blockIdx.y * TILE + r  - HALO;
    const int gj0 = (int)blockIdx.x * TILE + c0 - HALO;
    const int g   = gi * NY + gj0;

    const bool rowOK  = (gi >= 0) && (gi < NX);
    const bool colOK  = (gj0 >= 0) && (gj0 + 3 < NY);   // 4-groups never straddle the edge
    const bool inD    = rowOK && colOK;
    const bool fwdX   = (gi < NX - 1);
    const bool fwdY3  = (gj0 + 3 < NY - 1);
    const bool backX  = (gi > 0);
    const bool backY0 = (gj0 > 0);
    const bool haloUp   = (gi - 1 >= 0) && (gi - 1 < NX) && colOK;
    const bool haloLeft = rowOK && (gj0 - 1 >= 0);

    const float dpx = rowOK ? dprof(gi) : 0.0f;
    float damp[4], yy[4];
    #pragma unroll
    for (int k = 0; k < 4; ++k) {
        // fold bulk damping into the PML factor (one mul/step instead of two)
        damp[k] = inD ? dpx * dprof(gj0 + k) * kONE_MINUS_BD : 0.0f;
        yy[k]   = ((float)(gj0 + k) + 0.5f) * kDX;
    }
    const float xi = ((float)gi + 0.5f) * kDX;

    const bool owned = (r >= HALO) && (r < HALO + TILE) &&
                       (c0 >= HALO) && (c0 + 3 < HALO + TILE);

    // trajectory for this chunk (uniform)
    float trx[K], tryy[K];
    #pragma unroll
    for (int s = 0; s < K; ++s) { float2 t2 = traj[t0 + s]; trx[s] = t2.x; tryy[s] = t2.y; }

    // zero LDS (both buffers incl. pads)
    for (int idx = tid; idx < 2 * LROWS * LSTR; idx += NTHREADS)
        ((float*)s_vz)[idx] = 0.0f;

    // load state: vz + own strains + halo strains (row above, col left)
    float vz[4] = {0.f, 0.f, 0.f, 0.f};
    float sx[4] = {0.f, 0.f, 0.f, 0.f};
    float sy[4] = {0.f, 0.f, 0.f, 0.f};
    float sxm[4] = {0.f, 0.f, 0.f, 0.f};
    float sym = 0.f;
    if (!FIRST) {
        if (inD) {
            float4 v4 = *(const float4*)&vz_in[g];
            float4 a4 = *(const float4*)&sxz_in[g];
            float4 b4 = *(const float4*)&syz_in[g];
            vz[0] = v4.x; vz[1] = v4.y; vz[2] = v4.z; vz[3] = v4.w;
            sx[0] = a4.x; sx[1] = a4.y; sx[2] = a4.z; sx[3] = a4.w;
            sy[0] = b4.x; sy[1] = b4.y; sy[2] = b4.z; sy[3] = b4.w;
        }
        if (haloUp) {
            float4 m4 = *(const float4*)&sxz_in[g - NY];
            sxm[0] = m4.x; sxm[1] = m4.y; sxm[2] = m4.z; sxm[3] = m4.w;
        }
        if (haloLeft) sym = syz_in[g - 1];
    }
    __syncthreads();   // zero-fill complete before state write
    *(float4*)&s_vz[0][LIDX(r, c0)] = make_float4(vz[0], vz[1], vz[2], vz[3]);
    __syncthreads();

    #pragma unroll
    for (int s = 0; s < K; ++s) {
        const int cur = s & 1, nxt = cur ^ 1;
        const float x_t = trx[s], y_t = tryy[s];

        const float4 vp4 = *(const float4*)&s_vz[cur][LIDX(r + 1, c0)];
        const float4 vm4 = *(const float4*)&s_vz[cur][LIDX(r - 1, c0)];
        const float vl   = s_vz[cur][LIDX(r, c0 - 1)];
        const float vr   = s_vz[cur][LIDX(r, c0 + 4)];
        const float vpv[4] = {vp4.x, vp4.y, vp4.z, vp4.w};
        const float vmv[4] = {vm4.x, vm4.y, vm4.z, vm4.w};

        // forward differences at own cells
        float dvx[4], dvy[4];
        #pragma unroll
        for (int k = 0; k < 4; ++k) dvx[k] = fwdX ? (vpv[k] - vz[k]) * kINV_DX : 0.0f;
        dvy[0] = (vz[1] - vz[0]) * kINV_DY;
        dvy[1] = (vz[2] - vz[1]) * kINV_DY;
        dvy[2] = (vz[3] - vz[2]) * kINV_DY;
        dvy[3] = fwdY3 ? (vr - vz[3]) * kINV_DY : 0.0f;

        // own strain/sigma
        float gxv[4], gyv[4];
        #pragma unroll
        for (int k = 0; k < 4; ++k) {
            sx[k] += dvx[k] * kDT;
            sy[k] += dvy[k] * kDT;
            gxv[k] = kMU * sx[k] + kETA * dvx[k];
            gyv[k] = kMU * sy[k] + kETA * dvy[k];
        }

        // halo strain/sigma: row above (4 cells), col left (1 cell)
        float gxm[4];
        #pragma unroll
        for (int k = 0; k < 4; ++k) {
            const float dxm = (vz[k] - vmv[k]) * kINV_DX;
            sxm[k] += dxm * kDT;
            gxm[k] = kMU * sxm[k] + kETA * dxm;
        }
        const float dym = (vz[0] - vl) * kINV_DY;
        sym += dym * kDT;
        const float gym = kMU * sym + kETA * dym;

        // stress divergence (ds_dx + ds_dy), reference associativity
        float ds[4];
        ds[0] = (backX ? (gxv[0] - gxm[0]) * kINV_DX : 0.0f) +
                (backY0 ? (gyv[0] - gym) * kINV_DY : 0.0f);
        ds[1] = (backX ? (gxv[1] - gxm[1]) * kINV_DX : 0.0f) + (gyv[1] - gyv[0]) * kINV_DY;
        ds[2] = (backX ? (gxv[2] - gxm[2]) * kINV_DX : 0.0f) + (gyv[2] - gyv[1]) * kINV_DY;
        ds[3] = (backX ? (gxv[3] - gxm[3]) * kINV_DX : 0.0f) + (gyv[3] - gyv[2]) * kINV_DY;

        // Gaussian source (fast exp: v_exp path, error ~1ulp, far under threshold)
        const float rx  = xi - x_t;
        const float rx2 = rx * rx;
        #pragma unroll
        for (int k = 0; k < 4; ++k) {
            const float ry  = yy[k] - y_t;
            const float src = __expf((rx2 + ry * ry) * kNEG_INV_2SIG2);
            vz[k] = (vz[k] + kDT_OVER_RHO * (ds[k] + src)) * damp[k];
        }

        *(float4*)&s_vz[nxt][LIDX(r, c0)] = make_float4(vz[0], vz[1], vz[2], vz[3]);

        if (owned) {
            *(float4*)&out[(size_t)(t0 + s) * N_CELLS + g] =
                make_float4(vz[0], vz[1], vz[2], vz[3]);
            float4 sm;
            sm.x = sqrtf(gxv[0] * gxv[0] + gyv[0] * gyv[0] + kEPS);
            sm.y = sqrtf(gxv[1] * gxv[1] + gyv[1] * gyv[1] + kEPS);
            sm.z = sqrtf(gxv[2] * gxv[2] + gyv[2] * gyv[2] + kEPS);
            sm.w = sqrtf(gxv[3] * gxv[3] + gyv[3] * gyv[3] + kEPS);
            *(float4*)&out[(size_t)(N_STEPS + t0 + s) * N_CELLS + g] = sm;
        }
        __syncthreads();
    }

    if (!LAST && owned) {
        *(float4*)&vz_out[g]  = make_float4(vz[0], vz[1], vz[2], vz[3]);
        *(float4*)&sxz_out[g] = make_float4(sx[0], sx[1], sx[2], sx[3]);
        *(float4*)&syz_out[g] = make_float4(sy[0], sy[1], sy[2], sy[3]);
    }
}

extern "C" void kernel_launch(void* const* d_in, const int* in_sizes, int n_in,
                              void* d_out, int out_size, void* d_ws, size_t ws_size,
                              hipStream_t stream) {
    const float2* traj = (const float2*)d_in[0];
    float* out = (float*)d_out;
    float* ws  = (float*)d_ws;

    float* vz[2]  = { ws + 0 * N_CELLS, ws + 1 * N_CELLS };
    float* sxz[2] = { ws + 2 * N_CELLS, ws + 3 * N_CELLS };
    float* syz[2] = { ws + 4 * N_CELLS, ws + 5 * N_CELLS };

    const dim3 grid(NX / TILE, NY / TILE);

    // 18 chunks of 16 steps + 1 tail chunk of 12 = 300.
    // chunk l: reads set (l+1)&1, writes set l&1 (l=0 reads nothing).
    fused_kernel<16, true, false><<<grid, NTHREADS, 0, stream>>>(
        vz[1], sxz[1], syz[1], vz[0], sxz[0], syz[0], traj, 0, out);
    int l = 1, t0 = 16;
    for (; l < 18; ++l, t0 += 16) {
        const int rs = (l + 1) & 1, wsI = l & 1;
        fused_kernel<16, false, false><<<grid, NTHREADS, 0, stream>>>(
            vz[rs], sxz[rs], syz[rs], vz[wsI], sxz[wsI], syz[wsI], traj, t0, out);
    }
    {   // tail: 12 steps, no state store
        const int rs = (l + 1) & 1, wsI = l & 1;
        fused_kernel<12, false, true><<<grid, NTHREADS, 0, stream>>>(
            vz[rs], sxz[rs], syz[rs], vz[wsI], sxz[wsI], syz[wsI], traj, t0, out);
    }
}

// Round 6
// 262.578 us; speedup vs baseline: 4.1557x; 1.2109x over previous
//
#include <hip/hip_runtime.h>
#include <math.h>

#define NX 256
#define NY 256
#define N_STEPS 300
#define N_CELLS (NX * NY)
#define TILE 16
#define HALO 8
#define LSTR 36              // LDS row stride in floats
#define LROWS 34             // rows -1..32
#define LIDX(rr, cc) (((rr) + 1) * LSTR + ((cc) + 2))

// f32 constants (double-precision fold -> f32)
#define kINV_DX       1280.0f
#define kINV_DY       1280.0f
#define kDT           2.5e-5f
#define kMU           25000.0f
#define kETA          0.1f
#define kDT_OVER_RHO  2.5e-8f
#define kONE_MINUS_BD 0.99999975f
#define kNEG_INV_2SIG2 (-55555.5546875f)   // -1/(2*0.003^2)
#define kDX           7.8125e-4f
#define kEPS          1e-8f

// PML damping profile value for 1-D global index k (0..255)
__device__ __forceinline__ float dprof(int k) {
    int m = min(k, NX - 1 - k);
    if (m >= 20) return 1.0f;
    float arg = 3.14159265358979f * (float)(20 - m) / 20.0f;
    return 1.0f - 0.05f * (0.5f + 0.5f * cosf(arg));
}

template <int K, bool FIRST, bool LAST>
__global__ __launch_bounds__(512) void fused_kernel(
    const float* __restrict__ vz_in,
    const float* __restrict__ sxz_in,
    const float* __restrict__ syz_in,
    float* __restrict__ vz_out,
    float* __restrict__ sxz_out,
    float* __restrict__ syz_out,
    const float2* __restrict__ traj,
    int t0,
    float* __restrict__ out)
{
    __shared__ float s_vz[2][LROWS * LSTR];

    const int tid = threadIdx.x;
    const int r   = tid >> 4;            // region row, 0..31
    const int c0  = (tid & 15) << 1;     // region col base, 0,2,...,30

    const int gi  = (int)blockIdx.y * TILE + r  - HALO;
    const int gj0 = (int)blockIdx.x * TILE + c0 - HALO;
    const int g   = gi * NY + gj0;

    const bool rowOK  = (gi >= 0) && (gi < NX);
    const bool colOK  = (gj0 >= 0) && (gj0 < NY);   // pair never straddles (even)
    const bool inD    = rowOK && colOK;
    const bool fwdX   = (gi < NX - 1);
    const bool fwdY1  = (gj0 + 1 < NY - 1);
    const bool backX  = (gi > 0);
    const bool backY0 = (gj0 > 0);
    const bool haloUp   = (gi - 1 >= 0) && (gi - 1 < NX) && colOK;
    const bool haloLeft = rowOK && (gj0 - 1 >= 0);

    const float dpx   = rowOK ? dprof(gi) : 0.0f;
    // fold bulk damping into PML factor (one mul/step)
    const float damp0 = inD ? dpx * dprof(gj0) * kONE_MINUS_BD : 0.0f;
    const float damp1 = inD ? dpx * dprof(gj0 + 1) * kONE_MINUS_BD : 0.0f;
    const float xi    = ((float)gi + 0.5f) * kDX;
    const float yj0   = ((float)gj0 + 0.5f) * kDX;
    const float yj1   = ((float)gj0 + 1.5f) * kDX;

    const bool owned = (r >= HALO) && (r < HALO + TILE) &&
                       (c0 >= HALO) && (c0 + 1 < HALO + TILE);

    // trajectory for fused steps (uniform -> scalar regs)
    float trx[K], tryy[K];
    #pragma unroll
    for (int s = 0; s < K; ++s) { float2 t2 = traj[t0 + s]; trx[s] = t2.x; tryy[s] = t2.y; }

    // zero LDS (both buffers incl. pads)
    for (int idx = tid; idx < 2 * LROWS * LSTR; idx += 512)
        ((float*)s_vz)[idx] = 0.0f;

    // load state
    float vz0 = 0.f, vz1 = 0.f, sx0 = 0.f, sx1 = 0.f, sy0 = 0.f, sy1 = 0.f;
    float sxm0 = 0.f, sxm1 = 0.f, symv = 0.f;
    if (!FIRST) {
        if (inD) {
            float2 v2 = *(const float2*)&vz_in[g];  vz0 = v2.x; vz1 = v2.y;
            float2 a2 = *(const float2*)&sxz_in[g]; sx0 = a2.x; sx1 = a2.y;
            float2 b2 = *(const float2*)&syz_in[g]; sy0 = b2.x; sy1 = b2.y;
        }
        if (haloUp)   { float2 m2 = *(const float2*)&sxz_in[g - NY]; sxm0 = m2.x; sxm1 = m2.y; }
        if (haloLeft) { symv = syz_in[g - 1]; }
    }
    __syncthreads();
    *(float2*)&s_vz[0][LIDX(r, c0)] = make_float2(vz0, vz1);
    __syncthreads();

    // per-step history kept in registers; flushed to HBM after the loop so
    // the step-loop barriers never wait on vmcnt (HBM store drain).
    float hv0[K], hv1[K], hs0[K], hs1[K];

    #pragma unroll
    for (int s = 0; s < K; ++s) {
        const int cur = s & 1, nxt = cur ^ 1;
        const float x_t = trx[s], y_t = tryy[s];

        const float2 vp = *(const float2*)&s_vz[cur][LIDX(r + 1, c0)];
        const float2 vm = *(const float2*)&s_vz[cur][LIDX(r - 1, c0)];
        const float vr2 = s_vz[cur][LIDX(r, c0 + 2)];
        const float vl1 = s_vz[cur][LIDX(r, c0 - 1)];

        // forward differences at own cells
        const float dvx0 = fwdX  ? (vp.x - vz0) * kINV_DX : 0.0f;
        const float dvx1 = fwdX  ? (vp.y - vz1) * kINV_DX : 0.0f;
        const float dvy0 = (vz1 - vz0) * kINV_DY;
        const float dvy1 = fwdY1 ? (vr2 - vz1) * kINV_DY : 0.0f;

        // own strain/sigma
        sx0 += dvx0 * kDT; sx1 += dvx1 * kDT;
        sy0 += dvy0 * kDT; sy1 += dvy1 * kDT;
        const float gx0 = kMU * sx0 + kETA * dvx0;
        const float gx1 = kMU * sx1 + kETA * dvx1;
        const float gy0 = kMU * sy0 + kETA * dvy0;
        const float gy1 = kMU * sy1 + kETA * dvy1;

        // halo strain/sigma (row above, col left) maintained redundantly
        const float dxm0 = (vz0 - vm.x) * kINV_DX;
        const float dxm1 = (vz1 - vm.y) * kINV_DX;
        sxm0 += dxm0 * kDT; sxm1 += dxm1 * kDT;
        const float gxm0 = kMU * sxm0 + kETA * dxm0;
        const float gxm1 = kMU * sxm1 + kETA * dxm1;
        const float dym = (vz0 - vl1) * kINV_DY;
        symv += dym * kDT;
        const float gym = kMU * symv + kETA * dym;

        // stress divergence
        const float dsx0 = backX  ? (gx0 - gxm0) * kINV_DX : 0.0f;
        const float dsx1 = backX  ? (gx1 - gxm1) * kINV_DX : 0.0f;
        const float dsy0 = backY0 ? (gy0 - gym) * kINV_DY : 0.0f;
        const float dsy1 = (gy1 - gy0) * kINV_DY;

        // Gaussian source (v_exp fast path)
        const float rx  = xi - x_t;
        const float ry0 = yj0 - y_t;
        const float ry1 = yj1 - y_t;
        const float src0 = __expf((rx * rx + ry0 * ry0) * kNEG_INV_2SIG2);
        const float src1 = __expf((rx * rx + ry1 * ry1) * kNEG_INV_2SIG2);

        // velocity update
        vz0 = (vz0 + kDT_OVER_RHO * (dsx0 + dsy0 + src0)) * damp0;
        vz1 = (vz1 + kDT_OVER_RHO * (dsx1 + dsy1 + src1)) * damp1;

        *(float2*)&s_vz[nxt][LIDX(r, c0)] = make_float2(vz0, vz1);

        hv0[s] = vz0;
        hv1[s] = vz1;
        hs0[s] = sqrtf(gx0 * gx0 + gy0 * gy0 + kEPS);
        hs1[s] = sqrtf(gx1 * gx1 + gy1 * gy1 + kEPS);

        if (s + 1 < K) __syncthreads();   // last step needs no barrier
    }

    // flush history (off the barrier critical path)
    if (owned) {
        #pragma unroll
        for (int s = 0; s < K; ++s) {
            *(float2*)&out[(size_t)(t0 + s) * N_CELLS + g] = make_float2(hv0[s], hv1[s]);
            *(float2*)&out[(size_t)(N_STEPS + t0 + s) * N_CELLS + g] = make_float2(hs0[s], hs1[s]);
        }
        if (!LAST) {
            *(float2*)&vz_out[g]  = make_float2(vz0, vz1);
            *(float2*)&sxz_out[g] = make_float2(sx0, sx1);
            *(float2*)&syz_out[g] = make_float2(sy0, sy1);
        }
    }
}

extern "C" void kernel_launch(void* const* d_in, const int* in_sizes, int n_in,
                              void* d_out, int out_size, void* d_ws, size_t ws_size,
                              hipStream_t stream) {
    const float2* traj = (const float2*)d_in[0];
    float* out = (float*)d_out;
    float* ws  = (float*)d_ws;

    float* vz[2]  = { ws + 0 * N_CELLS, ws + 1 * N_CELLS };
    float* sxz[2] = { ws + 2 * N_CELLS, ws + 3 * N_CELLS };
    float* syz[2] = { ws + 4 * N_CELLS, ws + 5 * N_CELLS };

    const dim3 grid(NX / TILE, NY / TILE);

    // launch l reads set (l&1), writes set ((l&1)^1); l=0 ignores input (FIRST)
    int l = 0, t0 = 0;
    fused_kernel<8, true, false><<<grid, 512, 0, stream>>>(
        vz[0], sxz[0], syz[0], vz[1], sxz[1], syz[1], traj, 0, out);
    ++l; t0 += 8;
    for (; t0 + 8 <= N_STEPS - 4; t0 += 8, ++l) {
        const int a = l & 1, b = a ^ 1;
        fused_kernel<8, false, false><<<grid, 512, 0, stream>>>(
            vz[a], sxz[a], syz[a], vz[b], sxz[b], syz[b], traj, t0, out);
    }
    {   // tail: 4 steps, no state store
        const int a = l & 1, b = a ^ 1;
        fused_kernel<4, false, true><<<grid, 512, 0, stream>>>(
            vz[a], sxz[a], syz[a], vz[b], sxz[b], syz[b], traj, t0, out);
    }
}